// Round 15
// baseline (342.665 us; speedup 1.0000x reference)
//
#include <hip/hip_runtime.h>
#include <hip/hip_fp16.h>

#define D 128
#define H 4
#define EPC_LOG 13
#define EPC (1 << EPC_LOG)   // edges per chunk

typedef unsigned int uvec4 __attribute__((ext_vector_type(4)));

// ---------------------------------------------------------------------------
// Kernel 0: fast zero (fallback path only).
// ---------------------------------------------------------------------------
__global__ void zero_kernel(int* __restrict__ p, int n) {
    int i = blockIdx.x * blockDim.x + threadIdx.x;
    if (i < n) p[i] = 0;
}

// ---------------------------------------------------------------------------
// Kernel 1a (FALLBACK): global returning-atomic histogram (~100us measured:
// device atomic-throughput bound; R=8 replication and MLP=4 both null).
// ---------------------------------------------------------------------------
__global__ void count_kernel(const int* __restrict__ src,
                             int* __restrict__ counts,
                             unsigned short* __restrict__ rank16, int E) {
    int e = blockIdx.x * blockDim.x + threadIdx.x;
    if (e < E) rank16[e] = (unsigned short)atomicAdd(counts + src[e], 1);
}

// ---------------------------------------------------------------------------
// Kernel 1a': chunked LDS histogram — NO global atomics.
// Block c owns edges [c*EPC, (c+1)*EPC). Two passes over node halves with a
// 50KB LDS byte-histogram (word-packed LDS atomicAdd, returning). Writes the
// within-chunk rank (uchar) per edge and dumps hist[c][0..N) (uchar).
// ---------------------------------------------------------------------------
__global__ void count_lds_kernel(const int* __restrict__ src,
                                 unsigned char* __restrict__ hist,
                                 unsigned char* __restrict__ rank8,
                                 int N, int E) {
    extern __shared__ unsigned lds[];
    int c = blockIdx.x;
    int e_beg = c << EPC_LOG;
    int e_end = min(e_beg + EPC, E);
    int Nh = (N + 1) >> 1;
    int words = (Nh + 3) >> 2;
    for (int pass = 0; pass < 2; ++pass) {
        int base = pass * Nh;
        int lim = min(Nh, N - base);          // nodes in this half
        for (int i = threadIdx.x; i < words; i += blockDim.x) lds[i] = 0;
        __syncthreads();
        for (int e = e_beg + (int)threadIdx.x; e < e_end; e += blockDim.x) {
            int rel = src[e] - base;
            if (rel >= 0 && rel < lim) {
                unsigned sh = (unsigned)(rel & 3) * 8u;
                unsigned old = atomicAdd(&lds[rel >> 2], 1u << sh);
                rank8[e] = (unsigned char)((old >> sh) & 0xFFu);
            }
        }
        __syncthreads();
        unsigned char* dstp = hist + (size_t)c * N + base;
        bool aligned = (((size_t)dstp & 3) == 0);
        int wlim = (lim + 3) >> 2;
        for (int i = threadIdx.x; i < wlim; i += blockDim.x) {
            unsigned v = lds[i];
            int nb = lim - i * 4;
            if (aligned && nb >= 4) {
                *(unsigned*)(dstp + i * 4) = v;
            } else {
                nb = nb > 4 ? 4 : nb;
                for (int b = 0; b < nb; ++b)
                    dstp[i * 4 + b] = (unsigned char)((v >> (8 * b)) & 0xFFu);
            }
        }
        __syncthreads();
    }
}

// ---------------------------------------------------------------------------
// Kernel 1a'': per-node reduce over chunk histograms. counts[n] = sum_c
// hist[c][n]; hist[c][n] rewritten IN PLACE to the exclusive base (total
// degree <= ~50 fits uchar). uchar4-vectorized, coalesced.
// ---------------------------------------------------------------------------
__global__ void reduce_hist_kernel(unsigned char* __restrict__ hist,
                                   int* __restrict__ counts, int C, int N) {
    int n0 = (blockIdx.x * blockDim.x + threadIdx.x) * 4;
    if (n0 >= N) return;
    if (n0 + 4 <= N && (N & 3) == 0) {
        int t0 = 0, t1 = 0, t2 = 0, t3 = 0;
        for (int c = 0; c < C; ++c) {
            unsigned char* p = hist + (size_t)c * N + n0;
            uchar4 v = *(const uchar4*)p;
            *(uchar4*)p = make_uchar4((unsigned char)t0, (unsigned char)t1,
                                      (unsigned char)t2, (unsigned char)t3);
            t0 += v.x; t1 += v.y; t2 += v.z; t3 += v.w;
        }
        counts[n0] = t0; counts[n0 + 1] = t1; counts[n0 + 2] = t2; counts[n0 + 3] = t3;
    } else {
        for (int n = n0; n < N && n < n0 + 4; ++n) {
            int t = 0;
            for (int c = 0; c < C; ++c) {
                unsigned char* p = hist + (size_t)c * N + n;
                unsigned char v = *p; *p = (unsigned char)t; t += v;
            }
            counts[n] = t;
        }
    }
}

// ---------------------------------------------------------------------------
// Kernel 1b: per-node projections ps/pd + fp16 x-copy for gather.
// ---------------------------------------------------------------------------
__global__ void proj_kernel(const float* __restrict__ x,
                            const float* __restrict__ w,
                            const float* __restrict__ attn,
                            float* __restrict__ ps,
                            float* __restrict__ pd,
                            __half* __restrict__ xh,   // may be null
                            int N) {
    int node = (int)(((long long)blockIdx.x * blockDim.x + threadIdx.x) >> 6);
    int lane = threadIdx.x & 63;
    if (node >= N) return;
    float x0 = x[(size_t)node * D + lane];
    float x1 = x[(size_t)node * D + 64 + lane];
    if (xh) {
        xh[(size_t)node * D + lane]      = __float2half(x0);
        xh[(size_t)node * D + 64 + lane] = __float2half(x1);
    }
#pragma unroll
    for (int h = 0; h < H; ++h) {
        float hv0 = x0 * w[h * D + lane];
        float hv1 = x1 * w[h * D + 64 + lane];
        float psv = hv0 * attn[h * 2 * D + lane]     + hv1 * attn[h * 2 * D + 64 + lane];
        float pdv = hv0 * attn[h * 2 * D + D + lane] + hv1 * attn[h * 2 * D + D + 64 + lane];
#pragma unroll
        for (int off = 32; off > 0; off >>= 1) {
            psv += __shfl_xor(psv, off);
            pdv += __shfl_xor(pdv, off);
        }
        if (lane == 0) {
            ps[(size_t)node * H + h] = psv;
            pd[(size_t)node * H + h] = pdv;
        }
    }
}

// ---------------------------------------------------------------------------
// Scan pass 1: block-local exclusive scan of counts; block total to bsum.
// ---------------------------------------------------------------------------
__global__ void scan1_kernel(const int* __restrict__ counts,
                             int* __restrict__ offs,
                             int* __restrict__ bsum, int N) {
    __shared__ int wsum[16];
    __shared__ int woffi[16];
    int tid = threadIdx.x, lane = tid & 63, wid = tid >> 6;
    int i = blockIdx.x * 1024 + tid;
    int v = (i < N) ? counts[i] : 0;
    int acc = v;
#pragma unroll
    for (int d = 1; d < 64; d <<= 1) {
        int t = __shfl_up(acc, d);
        if (lane >= d) acc += t;
    }
    if (lane == 63) wsum[wid] = acc;
    __syncthreads();
    if (wid == 0) {
        int wv = (lane < 16) ? wsum[lane] : 0;
        int wacc = wv;
#pragma unroll
        for (int d = 1; d < 16; d <<= 1) {
            int t = __shfl_up(wacc, d);
            if (lane >= d) wacc += t;
        }
        if (lane < 16) woffi[lane] = wacc;
    }
    __syncthreads();
    int bexcl = (wid == 0) ? 0 : woffi[wid - 1];
    if (i < N) offs[i] = bexcl + (acc - v);
    if (tid == 0) bsum[blockIdx.x] = woffi[15];
}

// ---------------------------------------------------------------------------
// Scan pass 2: one wave scans block sums (supports nb <= 512).
// ---------------------------------------------------------------------------
__global__ void scan2_kernel(const int* __restrict__ bsum, int* __restrict__ boff, int nb) {
    int lane = threadIdx.x;
    int k = (nb + 63) >> 6;
    int local[8];
    int s = 0;
#pragma unroll 8
    for (int j = 0; j < k; ++j) {
        int idx = lane * k + j;
        local[j] = (idx < nb) ? bsum[idx] : 0;
        s += local[j];
    }
    int acc = s;
#pragma unroll
    for (int d = 1; d < 64; d <<= 1) {
        int t = __shfl_up(acc, d);
        if (lane >= d) acc += t;
    }
    int excl = acc - s;
#pragma unroll 8
    for (int j = 0; j < k; ++j) {
        int idx = lane * k + j;
        if (idx < nb) boff[idx] = excl;
        excl += local[j];
    }
}

// ---------------------------------------------------------------------------
// Scan pass 3: add block offsets; offs[N] = E.
// ---------------------------------------------------------------------------
__global__ void scan3_kernel(int* __restrict__ offs, const int* __restrict__ boff,
                             int N, int E) {
    int i = blockIdx.x * blockDim.x + threadIdx.x;
    if (i < N) offs[i] += boff[i >> 10];
    if (i == 0) offs[N] = E;
}

// ---------------------------------------------------------------------------
// Kernel 4: CSR scatter, atomic-free, 4 edges/thread.
// CH=1: pos = offs[s] + hist[e>>EPC_LOG][s] + rank8[e]
// CH=0: pos = offs[s] + rank16[e]
// ---------------------------------------------------------------------------
__device__ __forceinline__ void scatter_one(int s, int t, int rk,
                                            const int* __restrict__ offs,
                                            const float* __restrict__ ps,
                                            const float* __restrict__ pd,
                                            uvec4* __restrict__ ec) {
    int pos = offs[s] + rk;
    const float4 ps4 = *(const float4*)(ps + (size_t)s * H);
    const float4 pd4 = *(const float4*)(pd + (size_t)t * H);
    float s0 = ps4.x + pd4.x; s0 = s0 > 0.f ? s0 : 0.2f * s0;
    float s1 = ps4.y + pd4.y; s1 = s1 > 0.f ? s1 : 0.2f * s1;
    float s2 = ps4.z + pd4.z; s2 = s2 > 0.f ? s2 : 0.2f * s2;
    float s3 = ps4.w + pd4.w; s3 = s3 > 0.f ? s3 : 0.2f * s3;
    union { __half2 h[2]; uint2 u; } pk;
    pk.h[0] = __floats2half2_rn(__expf(-s0), __expf(-s1));
    pk.h[1] = __floats2half2_rn(__expf(-s2), __expf(-s3));
    uvec4 rec;
    rec.x = (unsigned)t; rec.y = pk.u.x; rec.z = pk.u.y; rec.w = 0u;
    ec[pos] = rec;
}

template <int CH>
__global__ void scatter_kernel(const int* __restrict__ src, const int* __restrict__ dst,
                               const unsigned char* __restrict__ rank8,
                               const unsigned short* __restrict__ rank16,
                               const unsigned char* __restrict__ hist,
                               const int* __restrict__ offs,
                               const float* __restrict__ ps, const float* __restrict__ pd,
                               uvec4* __restrict__ ec, int N, int E) {
    int e0 = (blockIdx.x * blockDim.x + threadIdx.x) * 4;
    if (e0 >= E) return;
    if (e0 + 4 <= E) {
        int4 s4 = *(const int4*)(src + e0);
        int4 t4 = *(const int4*)(dst + e0);
        int r0, r1, r2, r3;
        if (CH) {
            uchar4 rr = *(const uchar4*)(rank8 + e0);
            r0 = (int)hist[(size_t)((e0 + 0) >> EPC_LOG) * N + s4.x] + rr.x;
            r1 = (int)hist[(size_t)((e0 + 1) >> EPC_LOG) * N + s4.y] + rr.y;
            r2 = (int)hist[(size_t)((e0 + 2) >> EPC_LOG) * N + s4.z] + rr.z;
            r3 = (int)hist[(size_t)((e0 + 3) >> EPC_LOG) * N + s4.w] + rr.w;
        } else {
            ushort4 rr = *(const ushort4*)(rank16 + e0);
            r0 = rr.x; r1 = rr.y; r2 = rr.z; r3 = rr.w;
        }
        scatter_one(s4.x, t4.x, r0, offs, ps, pd, ec);
        scatter_one(s4.y, t4.y, r1, offs, ps, pd, ec);
        scatter_one(s4.z, t4.z, r2, offs, ps, pd, ec);
        scatter_one(s4.w, t4.w, r3, offs, ps, pd, ec);
    } else {
        for (int e = e0; e < E; ++e) {
            int rk;
            if (CH) rk = (int)hist[(size_t)(e >> EPC_LOG) * N + src[e]] + rank8[e];
            else    rk = rank16[e];
            scatter_one(src[e], dst[e], rk, offs, ps, pd, ec);
        }
    }
}

// ---------------------------------------------------------------------------
// Kernel 5: per-node gather + fused normalize, 8-deep pipelined (MLP=8).
// XH=1: x rows read as fp16. Plain cached loads/stores (round-9 NT hints
// regressed). Tail loop hand-written (round-7 lesson).
// ---------------------------------------------------------------------------
union HU { __half2 h; unsigned u; };

#define GDECL(j) uvec4 q##j; float2 v##j;
#define GLOAD(j) q##j = *((const uvec4*)ec + k + j);
#define GXLOADF(j) v##j = *(const float2*)(x + (size_t)q##j.x * D + lane2);
#define GXLOADH(j) { __half2 hv = *(const __half2*)(xh + (size_t)q##j.x * D + lane2); \
                     v##j = __half22float2(hv); }
#define GACC(j) { HU u01, u23; u01.u = q##j.y; u23.u = q##j.z;              \
    float e0 = __low2float(u01.h),  e1 = __high2float(u01.h);               \
    float e2 = __low2float(u23.h),  e3 = __high2float(u23.h);               \
    a0x += e0 * v##j.x; a0y += e0 * v##j.y; rs0 += e0;                      \
    a1x += e1 * v##j.x; a1y += e1 * v##j.y; rs1 += e1;                      \
    a2x += e2 * v##j.x; a2y += e2 * v##j.y; rs2 += e2;                      \
    a3x += e3 * v##j.x; a3y += e3 * v##j.y; rs3 += e3; }

template <int XH>
__global__ void gather_kernel(const float* __restrict__ x,
                              const __half* __restrict__ xh,
                              const float* __restrict__ w,
                              const int* __restrict__ offs,
                              const uvec4* __restrict__ ec,
                              float* __restrict__ out,
                              int N, int nodeBeg, int nodeEnd) {
    int node = nodeBeg + (int)(((long long)blockIdx.x * blockDim.x + threadIdx.x) >> 6);
    int lane = threadIdx.x & 63;
    if (node >= nodeEnd) return;
    int lane2 = lane * 2;
    float a0x = 0, a0y = 0, a1x = 0, a1y = 0, a2x = 0, a2y = 0, a3x = 0, a3y = 0;
    float rs0 = 0, rs1 = 0, rs2 = 0, rs3 = 0;
    int beg = offs[node], end = offs[node + 1];
    int k = beg;
    for (; k + 8 <= end; k += 8) {
        GDECL(0) GDECL(1) GDECL(2) GDECL(3) GDECL(4) GDECL(5) GDECL(6) GDECL(7)
        GLOAD(0) GLOAD(1) GLOAD(2) GLOAD(3) GLOAD(4) GLOAD(5) GLOAD(6) GLOAD(7)
        if (XH) { GXLOADH(0) GXLOADH(1) GXLOADH(2) GXLOADH(3) GXLOADH(4) GXLOADH(5) GXLOADH(6) GXLOADH(7) }
        else    { GXLOADF(0) GXLOADF(1) GXLOADF(2) GXLOADF(3) GXLOADF(4) GXLOADF(5) GXLOADF(6) GXLOADF(7) }
        GACC(0) GACC(1) GACC(2) GACC(3) GACC(4) GACC(5) GACC(6) GACC(7)
    }
    for (; k < end; ++k) {                 // hand-written tail: index k ONLY
        uvec4 q = *((const uvec4*)ec + k);
        float2 v;
        if (XH) { __half2 hv = *(const __half2*)(xh + (size_t)q.x * D + lane2); v = __half22float2(hv); }
        else    { v = *(const float2*)(x + (size_t)q.x * D + lane2); }
        HU u01, u23; u01.u = q.y; u23.u = q.z;
        float e0 = __low2float(u01.h),  e1 = __high2float(u01.h);
        float e2 = __low2float(u23.h),  e3 = __high2float(u23.h);
        a0x += e0 * v.x; a0y += e0 * v.y; rs0 += e0;
        a1x += e1 * v.x; a1y += e1 * v.y; rs1 += e1;
        a2x += e2 * v.x; a2y += e2 * v.y; rs2 += e2;
        a3x += e3 * v.x; a3y += e3 * v.y; rs3 += e3;
    }
    float i0 = 1.0f / rs0, i1 = 1.0f / rs1, i2 = 1.0f / rs2, i3 = 1.0f / rs3;
    size_t nd = (size_t)N * D;
    size_t b = (size_t)node * D + lane2;
    const float2 w0 = *(const float2*)(w + 0 * D + lane2);
    const float2 w1 = *(const float2*)(w + 1 * D + lane2);
    const float2 w2 = *(const float2*)(w + 2 * D + lane2);
    const float2 w3 = *(const float2*)(w + 3 * D + lane2);
    *(float2*)(out + 0 * nd + b) = make_float2(a0x * w0.x * i0, a0y * w0.y * i0);
    *(float2*)(out + 1 * nd + b) = make_float2(a1x * w1.x * i1, a1y * w1.y * i1);
    *(float2*)(out + 2 * nd + b) = make_float2(a2x * w2.x * i2, a2y * w2.y * i2);
    *(float2*)(out + 3 * nd + b) = make_float2(a3x * w3.x * i3, a3y * w3.y * i3);
}

extern "C" void kernel_launch(void* const* d_in, const int* in_sizes, int n_in,
                              void* d_out, int out_size, void* d_ws, size_t ws_size,
                              hipStream_t stream) {
    const float* x    = (const float*)d_in[0];
    const float* w    = (const float*)d_in[1];
    const float* attn = (const float*)d_in[2];
    const int*   edge = (const int*)d_in[3];

    int N = in_sizes[0] / D;
    int E = in_sizes[3] / 2;
    const int* src = edge;
    const int* dst = edge + E;
    float* out = (float*)d_out;

    int nb = (N + 1023) / 1024;
    int C  = (E + EPC - 1) >> EPC_LOG;     // chunks

    // Sizes (each block padded to 16B)
    auto pad16 = [](size_t v) { return (v + 15) & ~(size_t)15; };
    size_t sz_ec     = pad16((size_t)E * 16);
    size_t sz_xh     = pad16((size_t)N * D * 2);
    size_t sz_psd    = pad16((size_t)N * H * 4);
    size_t sz_counts = pad16((size_t)N * 4);
    size_t sz_offs   = pad16(((size_t)N + 2) * 4);
    size_t sz_nb     = pad16((size_t)nb * 4);
    size_t sz_rank   = pad16((size_t)E * 2);      // holds rank16 OR rank8
    size_t sz_hist   = pad16((size_t)C * N);      // uchar
    size_t need_base = sz_ec + 2 * sz_psd + sz_counts + sz_offs + 2 * sz_nb + sz_rank;
    bool use_xh   = ws_size >= need_base + sz_xh + 1024;
    bool use_lds  = ws_size >= need_base + (use_xh ? sz_xh : 0) + sz_hist + 1024;

    char* wsp = (char*)d_ws;
    uvec4* ec = (uvec4*)wsp;            wsp += sz_ec;
    __half* xh = nullptr;
    if (use_xh) { xh = (__half*)wsp;    wsp += sz_xh; }
    float* ps     = (float*)wsp;        wsp += sz_psd;
    float* pd     = (float*)wsp;        wsp += sz_psd;
    int*   counts = (int*)wsp;          wsp += sz_counts;
    int*   offs   = (int*)wsp;          wsp += sz_offs;
    int*   bsum   = (int*)wsp;          wsp += sz_nb;
    int*   boff   = (int*)wsp;          wsp += sz_nb;
    unsigned char*  rank8  = (unsigned char*)wsp;
    unsigned short* rank16 = (unsigned short*)wsp;  wsp += sz_rank;
    unsigned char*  hist   = (unsigned char*)wsp;

    if (use_lds) {
        int Nh = (N + 1) >> 1;
        size_t ldsBytes = (size_t)((Nh + 3) >> 2) * 4;
        count_lds_kernel<<<C, 256, ldsBytes, stream>>>(src, hist, rank8, N, E);
        proj_kernel<<<(N + 3) / 4, 256, 0, stream>>>(x, w, attn, ps, pd, xh, N);
        reduce_hist_kernel<<<(N / 4 + 255) / 256, 256, 0, stream>>>(hist, counts, C, N);
    } else {
        zero_kernel<<<(N + 255) / 256, 256, 0, stream>>>(counts, N);
        count_kernel<<<(E + 255) / 256, 256, 0, stream>>>(src, counts, rank16, E);
        proj_kernel<<<(N + 3) / 4, 256, 0, stream>>>(x, w, attn, ps, pd, xh, N);
    }
    scan1_kernel<<<nb, 1024, 0, stream>>>(counts, offs, bsum, N);
    scan2_kernel<<<1, 64, 0, stream>>>(bsum, boff, nb);
    scan3_kernel<<<(N + 255) / 256, 256, 0, stream>>>(offs, boff, N, E);
    if (use_lds)
        scatter_kernel<1><<<(E + 1023) / 1024, 256, 0, stream>>>(src, dst, rank8, rank16,
                                                                 hist, offs, ps, pd, ec, N, E);
    else
        scatter_kernel<0><<<(E + 1023) / 1024, 256, 0, stream>>>(src, dst, rank8, rank16,
                                                                 hist, offs, ps, pd, ec, N, E);
    int half = N / 2;
    if (use_xh) {
        gather_kernel<1><<<(half + 3) / 4, 256, 0, stream>>>(x, xh, w, offs, ec, out, N, 0, half);
        gather_kernel<1><<<((N - half) + 3) / 4, 256, 0, stream>>>(x, xh, w, offs, ec, out, N, half, N);
    } else {
        gather_kernel<0><<<(half + 3) / 4, 256, 0, stream>>>(x, xh, w, offs, ec, out, N, 0, half);
        gather_kernel<0><<<((N - half) + 3) / 4, 256, 0, stream>>>(x, xh, w, offs, ec, out, N, half, N);
    }
}

// Round 16
// 286.078 us; speedup vs baseline: 1.1978x; 1.1978x over previous
//
#include <hip/hip_runtime.h>
#include <hip/hip_fp16.h>

#define D 128
#define H 4

typedef unsigned int uvec4 __attribute__((ext_vector_type(4)));

// ---------------------------------------------------------------------------
// Kernel 0: fast zero (hipMemsetAsync's fill kernel measured 122us).
// ---------------------------------------------------------------------------
__global__ void zero_kernel(int* __restrict__ p, int n) {
    int i = blockIdx.x * blockDim.x + threadIdx.x;
    if (i < n) p[i] = 0;
}

// ---------------------------------------------------------------------------
// Kernel 1a: histogram of src with per-edge rank capture (returning atomic).
// ~100us, device-atomic-throughput bound (R=8 replication, MLP=4 batching,
// and LDS-chunked rebuild all null or worse -- rounds 11/12/15).
// ---------------------------------------------------------------------------
__global__ void count_kernel(const int* __restrict__ src,
                             int* __restrict__ counts,
                             unsigned short* __restrict__ rank, int E) {
    int e = blockIdx.x * blockDim.x + threadIdx.x;
    if (e < E) rank[e] = (unsigned short)atomicAdd(counts + src[e], 1);
}

// ---------------------------------------------------------------------------
// Kernel 1b: per-node projections ps/pd + fp16 x-copy for gather.
// ---------------------------------------------------------------------------
__global__ void proj_kernel(const float* __restrict__ x,
                            const float* __restrict__ w,
                            const float* __restrict__ attn,
                            float* __restrict__ ps,
                            float* __restrict__ pd,
                            __half* __restrict__ xh,   // may be null
                            int N) {
    int node = (int)(((long long)blockIdx.x * blockDim.x + threadIdx.x) >> 6);
    int lane = threadIdx.x & 63;
    if (node >= N) return;
    float x0 = x[(size_t)node * D + lane];
    float x1 = x[(size_t)node * D + 64 + lane];
    if (xh) {
        xh[(size_t)node * D + lane]      = __float2half(x0);
        xh[(size_t)node * D + 64 + lane] = __float2half(x1);
    }
#pragma unroll
    for (int h = 0; h < H; ++h) {
        float hv0 = x0 * w[h * D + lane];
        float hv1 = x1 * w[h * D + 64 + lane];
        float psv = hv0 * attn[h * 2 * D + lane]     + hv1 * attn[h * 2 * D + 64 + lane];
        float pdv = hv0 * attn[h * 2 * D + D + lane] + hv1 * attn[h * 2 * D + D + 64 + lane];
#pragma unroll
        for (int off = 32; off > 0; off >>= 1) {
            psv += __shfl_xor(psv, off);
            pdv += __shfl_xor(pdv, off);
        }
        if (lane == 0) {
            ps[(size_t)node * H + h] = psv;
            pd[(size_t)node * H + h] = pdv;
        }
    }
}

// ---------------------------------------------------------------------------
// Scan pass 1: block-local exclusive scan of counts; block total to bsum.
// ---------------------------------------------------------------------------
__global__ void scan1_kernel(const int* __restrict__ counts,
                             int* __restrict__ offs,
                             int* __restrict__ bsum, int N) {
    __shared__ int wsum[16];
    __shared__ int woffi[16];
    int tid = threadIdx.x, lane = tid & 63, wid = tid >> 6;
    int i = blockIdx.x * 1024 + tid;
    int v = (i < N) ? counts[i] : 0;
    int acc = v;
#pragma unroll
    for (int d = 1; d < 64; d <<= 1) {
        int t = __shfl_up(acc, d);
        if (lane >= d) acc += t;
    }
    if (lane == 63) wsum[wid] = acc;
    __syncthreads();
    if (wid == 0) {
        int wv = (lane < 16) ? wsum[lane] : 0;
        int wacc = wv;
#pragma unroll
        for (int d = 1; d < 16; d <<= 1) {
            int t = __shfl_up(wacc, d);
            if (lane >= d) wacc += t;
        }
        if (lane < 16) woffi[lane] = wacc;
    }
    __syncthreads();
    int bexcl = (wid == 0) ? 0 : woffi[wid - 1];
    if (i < N) offs[i] = bexcl + (acc - v);
    if (tid == 0) bsum[blockIdx.x] = woffi[15];
}

// ---------------------------------------------------------------------------
// Scan pass 2: one wave scans block sums (supports nb <= 512).
// ---------------------------------------------------------------------------
__global__ void scan2_kernel(const int* __restrict__ bsum, int* __restrict__ boff, int nb) {
    int lane = threadIdx.x;
    int k = (nb + 63) >> 6;
    int local[8];
    int s = 0;
#pragma unroll 8
    for (int j = 0; j < k; ++j) {
        int idx = lane * k + j;
        local[j] = (idx < nb) ? bsum[idx] : 0;
        s += local[j];
    }
    int acc = s;
#pragma unroll
    for (int d = 1; d < 64; d <<= 1) {
        int t = __shfl_up(acc, d);
        if (lane >= d) acc += t;
    }
    int excl = acc - s;
#pragma unroll 8
    for (int j = 0; j < k; ++j) {
        int idx = lane * k + j;
        if (idx < nb) boff[idx] = excl;
        excl += local[j];
    }
}

// ---------------------------------------------------------------------------
// Scan pass 3: add block offsets; offs[N] = E.
// ---------------------------------------------------------------------------
__global__ void scan3_kernel(int* __restrict__ offs, const int* __restrict__ boff,
                             int N, int E) {
    int i = blockIdx.x * blockDim.x + threadIdx.x;
    if (i < N) offs[i] += boff[i >> 10];
    if (i == 0) offs[N] = E;
}

// ---------------------------------------------------------------------------
// Kernel 4: CSR scatter, atomic-free, 4 edges/thread.
// pos = offs[src] + rank[e]; record = {dst, e01_fp16, e23_fp16, 0}.
// ---------------------------------------------------------------------------
__device__ __forceinline__ void scatter_one(int s, int t, int rk,
                                            const int* __restrict__ offs,
                                            const float* __restrict__ ps,
                                            const float* __restrict__ pd,
                                            uvec4* __restrict__ ec) {
    int pos = offs[s] + rk;
    const float4 ps4 = *(const float4*)(ps + (size_t)s * H);
    const float4 pd4 = *(const float4*)(pd + (size_t)t * H);
    float s0 = ps4.x + pd4.x; s0 = s0 > 0.f ? s0 : 0.2f * s0;
    float s1 = ps4.y + pd4.y; s1 = s1 > 0.f ? s1 : 0.2f * s1;
    float s2 = ps4.z + pd4.z; s2 = s2 > 0.f ? s2 : 0.2f * s2;
    float s3 = ps4.w + pd4.w; s3 = s3 > 0.f ? s3 : 0.2f * s3;
    union { __half2 h[2]; uint2 u; } pk;
    pk.h[0] = __floats2half2_rn(__expf(-s0), __expf(-s1));
    pk.h[1] = __floats2half2_rn(__expf(-s2), __expf(-s3));
    uvec4 rec;
    rec.x = (unsigned)t; rec.y = pk.u.x; rec.z = pk.u.y; rec.w = 0u;
    ec[pos] = rec;
}

__global__ void scatter_kernel(const int* __restrict__ src, const int* __restrict__ dst,
                               const unsigned short* __restrict__ rank,
                               const int* __restrict__ offs,
                               const float* __restrict__ ps, const float* __restrict__ pd,
                               uvec4* __restrict__ ec, int E) {
    int e0 = (blockIdx.x * blockDim.x + threadIdx.x) * 4;
    if (e0 >= E) return;
    if (e0 + 4 <= E) {
        int4 s4 = *(const int4*)(src + e0);
        int4 t4 = *(const int4*)(dst + e0);
        ushort4 r4 = *(const ushort4*)(rank + e0);
        scatter_one(s4.x, t4.x, r4.x, offs, ps, pd, ec);
        scatter_one(s4.y, t4.y, r4.y, offs, ps, pd, ec);
        scatter_one(s4.z, t4.z, r4.z, offs, ps, pd, ec);
        scatter_one(s4.w, t4.w, r4.w, offs, ps, pd, ec);
    } else {
        for (int e = e0; e < E; ++e)
            scatter_one(src[e], dst[e], rank[e], offs, ps, pd, ec);
    }
}

// ---------------------------------------------------------------------------
// Kernel 5: gather, TWO nodes per wave (half-wave per node, 4 cols/lane).
// Per 8-edge batch: 8 ec loads + 8 x-row loads per half -> 16 independent
// x-loads in flight per wave (2x round-14 MLP), half the wave count.
// Predicated batches (valid ? e : 0, index clamped to 0) -- NO tail loop
// (self-loops guarantee deg>=1 so ec[0] clamp is always in-bounds).
// XH=1: x rows read as fp16 (8B/lane). Plain cached loads (NT regressed, r9).
// ---------------------------------------------------------------------------
union HU { __half2 h; unsigned u; };
union XU { uint2 u; __half2 h[2]; };

template <int XH>
__global__ void gather2_kernel(const float* __restrict__ x,
                               const __half* __restrict__ xh,
                               const float* __restrict__ w,
                               const int* __restrict__ offs,
                               const uvec4* __restrict__ ec,
                               float* __restrict__ out,
                               int N) {
    int wv = (int)(((long long)blockIdx.x * blockDim.x + threadIdx.x) >> 6);
    int lane = threadIdx.x & 63;
    int half = lane >> 5;
    int l4 = (lane & 31) * 4;            // this lane's 4 columns
    int node = wv * 2 + half;
    bool active = node < N;
    int beg = 0, end = 0;
    if (active) { beg = offs[node]; end = offs[node + 1]; }
    int myIters = (end - beg + 7) >> 3;
    int otherIters = __shfl_xor(myIters, 32);
    int iters = myIters > otherIters ? myIters : otherIters;

    float a00 = 0, a01 = 0, a02 = 0, a03 = 0, rs0 = 0;
    float a10 = 0, a11 = 0, a12 = 0, a13 = 0, rs1 = 0;
    float a20 = 0, a21 = 0, a22 = 0, a23 = 0, rs2 = 0;
    float a30 = 0, a31 = 0, a32 = 0, a33 = 0, rs3 = 0;

    for (int it = 0; it < iters; ++it) {
        int kb = beg + (it << 3);
        uvec4 q[8];
#pragma unroll
        for (int j = 0; j < 8; ++j) {
            int kk = kb + j;
            q[j] = ec[kk < end ? kk : 0];
        }
        uint2 xv[8];
        float4 xf[8];
#pragma unroll
        for (int j = 0; j < 8; ++j) {
            if (XH) xv[j] = *(const uint2*)(xh + (size_t)q[j].x * D + l4);
            else    xf[j] = *(const float4*)(x + (size_t)q[j].x * D + l4);
        }
#pragma unroll
        for (int j = 0; j < 8; ++j) {
            int kk = kb + j;
            bool valid = kk < end;
            HU u01, u23;
            u01.u = valid ? q[j].y : 0u;
            u23.u = valid ? q[j].z : 0u;
            float e0 = __low2float(u01.h), e1 = __high2float(u01.h);
            float e2 = __low2float(u23.h), e3 = __high2float(u23.h);
            float c0, c1, c2, c3;
            if (XH) {
                XU xu; xu.u = xv[j];
                float2 p01 = __half22float2(xu.h[0]);
                float2 p23 = __half22float2(xu.h[1]);
                c0 = p01.x; c1 = p01.y; c2 = p23.x; c3 = p23.y;
            } else {
                c0 = xf[j].x; c1 = xf[j].y; c2 = xf[j].z; c3 = xf[j].w;
            }
            a00 += e0 * c0; a01 += e0 * c1; a02 += e0 * c2; a03 += e0 * c3; rs0 += e0;
            a10 += e1 * c0; a11 += e1 * c1; a12 += e1 * c2; a13 += e1 * c3; rs1 += e1;
            a20 += e2 * c0; a21 += e2 * c1; a22 += e2 * c2; a23 += e2 * c3; rs2 += e2;
            a30 += e3 * c0; a31 += e3 * c1; a32 += e3 * c2; a33 += e3 * c3; rs3 += e3;
        }
    }

    if (active) {
        float i0 = 1.0f / rs0, i1 = 1.0f / rs1, i2 = 1.0f / rs2, i3 = 1.0f / rs3;
        size_t nd = (size_t)N * D;
        size_t b = (size_t)node * D + l4;
        float4 w0 = *(const float4*)(w + 0 * D + l4);
        float4 w1 = *(const float4*)(w + 1 * D + l4);
        float4 w2 = *(const float4*)(w + 2 * D + l4);
        float4 w3 = *(const float4*)(w + 3 * D + l4);
        *(float4*)(out + 0 * nd + b) = make_float4(a00 * w0.x * i0, a01 * w0.y * i0,
                                                   a02 * w0.z * i0, a03 * w0.w * i0);
        *(float4*)(out + 1 * nd + b) = make_float4(a10 * w1.x * i1, a11 * w1.y * i1,
                                                   a12 * w1.z * i1, a13 * w1.w * i1);
        *(float4*)(out + 2 * nd + b) = make_float4(a20 * w2.x * i2, a21 * w2.y * i2,
                                                   a22 * w2.z * i2, a23 * w2.w * i2);
        *(float4*)(out + 3 * nd + b) = make_float4(a30 * w3.x * i3, a31 * w3.y * i3,
                                                   a32 * w3.z * i3, a33 * w3.w * i3);
    }
}

extern "C" void kernel_launch(void* const* d_in, const int* in_sizes, int n_in,
                              void* d_out, int out_size, void* d_ws, size_t ws_size,
                              hipStream_t stream) {
    const float* x    = (const float*)d_in[0];
    const float* w    = (const float*)d_in[1];
    const float* attn = (const float*)d_in[2];
    const int*   edge = (const int*)d_in[3];

    int N = in_sizes[0] / D;
    int E = in_sizes[3] / 2;
    const int* src = edge;
    const int* dst = edge + E;
    float* out = (float*)d_out;

    int nb = (N + 1023) / 1024;

    auto pad16 = [](size_t v) { return (v + 15) & ~(size_t)15; };
    size_t sz_ec     = pad16((size_t)E * 16);
    size_t sz_xh     = pad16((size_t)N * D * 2);
    size_t sz_psd    = pad16((size_t)N * H * 4);
    size_t sz_counts = pad16((size_t)N * 4);
    size_t sz_offs   = pad16(((size_t)N + 2) * 4);
    size_t sz_nb     = pad16((size_t)nb * 4);
    size_t sz_rank   = pad16((size_t)E * 2);
    size_t need_base = sz_ec + 2 * sz_psd + sz_counts + sz_offs + 2 * sz_nb + sz_rank;
    bool use_xh = ws_size >= need_base + sz_xh + 1024;

    char* wsp = (char*)d_ws;
    uvec4* ec = (uvec4*)wsp;            wsp += sz_ec;
    __half* xh = nullptr;
    if (use_xh) { xh = (__half*)wsp;    wsp += sz_xh; }
    float* ps     = (float*)wsp;        wsp += sz_psd;
    float* pd     = (float*)wsp;        wsp += sz_psd;
    int*   counts = (int*)wsp;          wsp += sz_counts;
    int*   offs   = (int*)wsp;          wsp += sz_offs;
    int*   bsum   = (int*)wsp;          wsp += sz_nb;
    int*   boff   = (int*)wsp;          wsp += sz_nb;
    unsigned short* rank = (unsigned short*)wsp;

    zero_kernel<<<(N + 255) / 256, 256, 0, stream>>>(counts, N);
    count_kernel<<<(E + 255) / 256, 256, 0, stream>>>(src, counts, rank, E);
    proj_kernel<<<(N + 3) / 4, 256, 0, stream>>>(x, w, attn, ps, pd, xh, N);
    scan1_kernel<<<nb, 1024, 0, stream>>>(counts, offs, bsum, N);
    scan2_kernel<<<1, 64, 0, stream>>>(bsum, boff, nb);
    scan3_kernel<<<(N + 255) / 256, 256, 0, stream>>>(offs, boff, N, E);
    scatter_kernel<<<(E + 1023) / 1024, 256, 0, stream>>>(src, dst, rank, offs,
                                                          ps, pd, ec, E);
    int waves = (N + 1) / 2;
    int gblocks = (waves + 3) / 4;
    if (use_xh)
        gather2_kernel<1><<<gblocks, 256, 0, stream>>>(x, xh, w, offs, ec, out, N);
    else
        gather2_kernel<0><<<gblocks, 256, 0, stream>>>(x, xh, w, offs, ec, out, N);
}